// Round 5
// baseline (376.621 us; speedup 1.0000x reference)
//
#include <hip/hip_runtime.h>
#include <stdint.h>

// SpikeMLP via exact fixed-point i8 MFMA, register-blocked.
// w -> n = rint(w * 2^42), 5 signed base-256 digits. Spikes are {0,1} i8.
// Per-limb i32 MFMA sums exact; i64 Horner exact; f64 scale exact. Only
// deviation vs f64-np reference: 2^-43 weight quantization (~1e-4 expected
// spike flips). Verified absmax 0.0 in round 4 with identical numerics.
// Wave tile 64x64 (2x2 of 32x32) so each fragment feeds 2 MFMAs; fragment-
// ordered LDS (addr = lane*16) makes all LDS traffic conflict-free.

typedef int v4i __attribute__((ext_vector_type(4)));
typedef int v16i __attribute__((ext_vector_type(16)));

#define TT 16
constexpr int KD = 2048;
constexpr double SCALE = 4398046511104.0;   // 2^42

// ---------- weight -> 5 signed-digit i8 planes ----------
__global__ __launch_bounds__(256)
void prep_limbs(const float* __restrict__ W, int8_t* __restrict__ dst, int total) {
  const int i4 = (blockIdx.x * 256 + threadIdx.x) * 4;
  if (i4 >= total) return;
  const float4 wv = *reinterpret_cast<const float4*>(W + i4);
  long long n[4];
  n[0] = (long long)rint((double)wv.x * SCALE);
  n[1] = (long long)rint((double)wv.y * SCALE);
  n[2] = (long long)rint((double)wv.z * SCALE);
  n[3] = (long long)rint((double)wv.w * SCALE);
#pragma unroll
  for (int l = 0; l < 5; ++l) {
    char c[4];
#pragma unroll
    for (int e = 0; e < 4; ++e) {
      const int d = (int)((n[e] + 128) & 255) - 128;   // balanced digit
      c[e] = (char)d;
      n[e] = (n[e] - d) >> 8;
    }
    *reinterpret_cast<char4*>(dst + (size_t)l * total + i4) =
        make_char4(c[0], c[1], c[2], c[3]);
  }
}

// ---------- [B][IN][T] f32 -> [(b,t)][IN] i8 spikes ----------
__global__ __launch_bounds__(256)
void transpose_x_i8(const float* __restrict__ in, int8_t* __restrict__ out) {
  const int idx = blockIdx.x * 256 + threadIdx.x;       // (b, i), i fastest
  const float4* src = reinterpret_cast<const float4*>(in) + (size_t)idx * 4;
  float4 v[4];
  v[0] = src[0]; v[1] = src[1]; v[2] = src[2]; v[3] = src[3];
  const float* f = reinterpret_cast<const float*>(v);
  const int b = idx >> 11, i = idx & 2047;
  int8_t* dst = out + (size_t)b * TT * KD + i;
#pragma unroll
  for (int t = 0; t < TT; ++t) dst[(size_t)t * KD] = (int8_t)f[t];
}

static __device__ __forceinline__ v16i zero16() {
  v16i z;
#pragma unroll
  for (int i = 0; i < 16; ++i) z[i] = 0;
  return z;
}

// ---------- fused i8 GEMM (5 limbs), 2x2 register blocking + CLIF scan ----
// Block: 256 threads / 4 waves; BM=BN=128. Wave (wy=w>>1, wx=w&1) owns
// msubs {2wy,2wy+1} x nsubs {2wx,2wx+1}. A and B staged fragment-ordered in
// LDS, double-buffered, 1 barrier per K-tile, prefetch 2 tiles ahead.
template<int N, bool FINAL>
__global__ __launch_bounds__(256, 1)
void gemm_scan_i8(const int8_t* __restrict__ A,    // [4096][2048] spikes
                  const int8_t* __restrict__ WL,   // [5][N][2048] limbs
                  const float* __restrict__ bias,  // [N]
                  void* __restrict__ outp) {
  __shared__ union SM {
    struct {
      int8_t a[2][4 * 1024];    // [buf][msub*1024 + lane*16]       8 KB
      int8_t b[2][20 * 1024];   // [buf][(l*4+nsub)*1024 + lane*16] 40 KB
    } s;
    double c[4][32 * 33];       // per-wave epilogue C tile         33.8 KB
  } sm;

  const int tid = threadIdx.x;
  const int lane = tid & 63;
  const int w = tid >> 6;
  const int wy = w >> 1, wx = w & 1;
  const int m0 = blockIdx.x * 128;
  const int n0 = blockIdx.y * 128;

  // staging: thread -> row = tid>>1 (0..127), k-half kh = tid&1 (16 B each)
  const int row = tid >> 1, kh = tid & 1;
  const size_t lst = (size_t)N * KD;                 // limb plane stride
  const int8_t* Asrc = A + (size_t)(m0 + row) * KD + kh * 16;
  const int8_t* Bsrc = WL + (size_t)(n0 + row) * KD + kh * 16;
  const int sdst = (row >> 5) * 1024 + kh * 512 + (row & 31) * 16;

  v16i acc[5][2][2];
#pragma unroll
  for (int l = 0; l < 5; ++l)
#pragma unroll
    for (int mi = 0; mi < 2; ++mi)
#pragma unroll
      for (int ni = 0; ni < 2; ++ni) acc[l][mi][ni] = zero16();

  v4i sa, sb[5];
  // prologue: tile 0 -> regs -> buf0; tile 1 -> regs
  sa = *(const v4i*)Asrc;
#pragma unroll
  for (int l = 0; l < 5; ++l) sb[l] = *(const v4i*)(Bsrc + l * lst);
  *(v4i*)(sm.s.a[0] + sdst) = sa;
#pragma unroll
  for (int l = 0; l < 5; ++l) *(v4i*)(sm.s.b[0] + l * 4096 + sdst) = sb[l];
  sa = *(const v4i*)(Asrc + 32);
#pragma unroll
  for (int l = 0; l < 5; ++l) sb[l] = *(const v4i*)(Bsrc + l * lst + 32);
  __syncthreads();

  for (int t = 0; t < KD / 32; ++t) {
    const int cur = t & 1;
    const int8_t* ab = sm.s.a[cur];
    const int8_t* bb = sm.s.b[cur];
    const v4i a0 = *(const v4i*)(ab + (wy * 2 + 0) * 1024 + lane * 16);
    const v4i a1 = *(const v4i*)(ab + (wy * 2 + 1) * 1024 + lane * 16);
#pragma unroll
    for (int l = 0; l < 5; ++l) {
      const v4i b0 = *(const v4i*)(bb + (l * 4 + wx * 2 + 0) * 1024 + lane * 16);
      const v4i b1 = *(const v4i*)(bb + (l * 4 + wx * 2 + 1) * 1024 + lane * 16);
      acc[l][0][0] = __builtin_amdgcn_mfma_i32_32x32x32_i8(a0, b0, acc[l][0][0], 0, 0, 0);
      acc[l][0][1] = __builtin_amdgcn_mfma_i32_32x32x32_i8(a0, b1, acc[l][0][1], 0, 0, 0);
      acc[l][1][0] = __builtin_amdgcn_mfma_i32_32x32x32_i8(a1, b0, acc[l][1][0], 0, 0, 0);
      acc[l][1][1] = __builtin_amdgcn_mfma_i32_32x32x32_i8(a1, b1, acc[l][1][1], 0, 0, 0);
    }
    if (t < KD / 32 - 1) {          // stage tile t+1 into other buffer
      *(v4i*)(sm.s.a[cur ^ 1] + sdst) = sa;
#pragma unroll
      for (int l = 0; l < 5; ++l) *(v4i*)(sm.s.b[cur ^ 1] + l * 4096 + sdst) = sb[l];
    }
    if (t < KD / 32 - 2) {          // prefetch tile t+2 (one full iter of cover)
      sa = *(const v4i*)(Asrc + (t + 2) * 32);
#pragma unroll
      for (int l = 0; l < 5; ++l) sb[l] = *(const v4i*)(Bsrc + l * lst + (t + 2) * 32);
    }
    __syncthreads();
  }

  // ---- decode D layout at runtime (uniform-byte MFMAs, permutation-immune)
  const int rep = (lane & 31) * 0x01010101;
  v4i rowv; rowv[0] = rep; rowv[1] = rep; rowv[2] = rep; rowv[3] = rep;
  v4i onev; onev[0] = 0x01010101; onev[1] = 0x01010101;
            onev[2] = 0x01010101; onev[3] = 0x01010101;
  const v16i drow = __builtin_amdgcn_mfma_i32_32x32x32_i8(rowv, onev, zero16(), 0, 0, 0);
  const v16i dcol = __builtin_amdgcn_mfma_i32_32x32x32_i8(onev, rowv, zero16(), 0, 0, 0);

  // ---- epilogue: 4 passes (mi, ni); per pass: combine limbs exactly,
  //      scatter f64 into per-wave LDS tile, CLIF-scan 32 cols x 2 batches.
  const int col = lane & 31;
  const int bl = lane >> 5;
  double* cw = sm.c[w];
#pragma unroll
  for (int mi = 0; mi < 2; ++mi)
#pragma unroll
    for (int ni = 0; ni < 2; ++ni) {
      __syncthreads();             // LDS region free (staging dead / prev pass)
#pragma unroll
      for (int i = 0; i < 16; ++i) {
        long long ts = acc[4][mi][ni][i];
        ts = (ts << 8) + acc[3][mi][ni][i];
        ts = (ts << 8) + acc[2][mi][ni][i];
        ts = (ts << 8) + acc[1][mi][ni][i];
        ts = (ts << 8) + acc[0][mi][ni][i];
        cw[(drow[i] >> 5) * 33 + (dcol[i] >> 5)] = (double)ts * 0x1p-42;
      }
      __syncthreads();

      const int gn = n0 + (wx * 2 + ni) * 32 + col;     // global column
      const int gm = m0 + (wy * 2 + mi) * 32 + bl * 16; // global row of t=0
      const double bj = (double)bias[gn];
      double cc = 0.0, vv = 0.0, ss = 0.0;
      if (!FINAL) {
        int8_t* so = (int8_t*)outp;
#pragma unroll
        for (int t = 0; t < TT; ++t) {
          const double x = cw[(bl * 16 + t) * 33 + col] + bj;
          cc = cc * 0.5 + x;                    // NEURON_CDECAY
          vv = vv * 0.75 * (1.0 - ss) + cc;     // NEURON_VDECAY, soft reset
          ss = (vv > 0.5) ? 1.0 : 0.0;          // NEURON_VTH
          so[(size_t)(gm + t) * N + gn] = (int8_t)ss;
        }
      } else {
        float tot = 0.0f;
#pragma unroll
        for (int t = 0; t < TT; ++t) {
          const double x = cw[(bl * 16 + t) * 33 + col] + bj;
          cc = cc * 0.5 + x;
          vv = vv * 0.75 * (1.0 - ss) + cc;
          ss = (vv > 0.5) ? 1.0 : 0.0;
          tot += (float)ss;
        }
        ((float*)outp)[(size_t)(gm / TT) * N + gn] = tot * 0.0625f;
      }
    }
}

extern "C" void kernel_launch(void* const* d_in, const int* in_sizes, int n_in,
                              void* d_out, int out_size, void* d_ws, size_t ws_size,
                              hipStream_t stream) {
  const float* X  = (const float*)d_in[0];  // [256][2048][16]
  const float* W0 = (const float*)d_in[1];  // [2048][2048]
  const float* b0 = (const float*)d_in[2];
  const float* W1 = (const float*)d_in[3];  // [2048][2048]
  const float* b1 = (const float*)d_in[4];
  const float* Wo = (const float*)d_in[5];  // [1024][2048]
  const float* bo = (const float*)d_in[6];
  float* out = (float*)d_out;               // [256][1024]

  int8_t* base = (int8_t*)d_ws;
  int8_t* Xi8 = base;                                   // 8.39 MB
  int8_t* S0  = base + (size_t)8388608;                 // 8.39 MB
  int8_t* S1  = Xi8;                                    // reuse after layer 0
  int8_t* L0  = base + (size_t)16777216;                // 21 MB
  int8_t* L1  = base + (size_t)37748736;                // 21 MB
  int8_t* Lo  = base + (size_t)58720256;                // 10.5 MB

  prep_limbs<<<(2048 * 2048 / 4 + 255) / 256, 256, 0, stream>>>(W0, L0, 2048 * 2048);
  prep_limbs<<<(2048 * 2048 / 4 + 255) / 256, 256, 0, stream>>>(W1, L1, 2048 * 2048);
  prep_limbs<<<(1024 * 2048 / 4 + 255) / 256, 256, 0, stream>>>(Wo, Lo, 1024 * 2048);
  transpose_x_i8<<<2048, 256, 0, stream>>>(X, Xi8);

  gemm_scan_i8<2048, false><<<dim3(32, 16), 256, 0, stream>>>(Xi8, L0, b0, S0);
  gemm_scan_i8<2048, false><<<dim3(32, 16), 256, 0, stream>>>(S0, L1, b1, S1);
  gemm_scan_i8<1024, true ><<<dim3(32, 8),  256, 0, stream>>>(S1, Lo, bo, out);
}

// Round 6
// 262.782 us; speedup vs baseline: 1.4332x; 1.4332x over previous
//
#include <hip/hip_runtime.h>
#include <stdint.h>

// SpikeMLP via exact fixed-point i8 MFMA.
// w -> n = rint(w * 2^42), 5 signed base-256 digits; spikes are {0,1} i8.
// Per-limb i32 MFMA sums exact; i64 Horner exact; f64 scale exact. Numerics
// identical to rounds 4/5 (both absmax 0.0).
// Structure: 512 thr / 8 waves; BM=256, BN=64; wave (wy=w>>1, nsub=w&1) owns
// a 64x32 output tile (2x1 of 32x32) -> each B-fragment feeds 2 MFMAs.
// All LDS traffic fragment-ordered (addr = lane*16): conflict-free.
// acc = 5*2*16 = 160 regs -> fits 2 waves/SIMD (launch_bounds(512,2)).

typedef int v4i __attribute__((ext_vector_type(4)));
typedef int v16i __attribute__((ext_vector_type(16)));

#define TT 16
constexpr int KD = 2048;
constexpr double SCALE = 4398046511104.0;   // 2^42

// ---------- weight -> 5 signed-digit i8 planes ----------
__global__ __launch_bounds__(256)
void prep_limbs(const float* __restrict__ W, int8_t* __restrict__ dst, int total) {
  const int i4 = (blockIdx.x * 256 + threadIdx.x) * 4;
  if (i4 >= total) return;
  const float4 wv = *reinterpret_cast<const float4*>(W + i4);
  long long n[4];
  n[0] = (long long)rint((double)wv.x * SCALE);
  n[1] = (long long)rint((double)wv.y * SCALE);
  n[2] = (long long)rint((double)wv.z * SCALE);
  n[3] = (long long)rint((double)wv.w * SCALE);
#pragma unroll
  for (int l = 0; l < 5; ++l) {
    char c[4];
#pragma unroll
    for (int e = 0; e < 4; ++e) {
      const int d = (int)((n[e] + 128) & 255) - 128;   // balanced digit
      c[e] = (char)d;
      n[e] = (n[e] - d) >> 8;
    }
    *reinterpret_cast<char4*>(dst + (size_t)l * total + i4) =
        make_char4(c[0], c[1], c[2], c[3]);
  }
}

// ---------- [B][IN][T] f32 -> [(b,t)][IN] i8 spikes ----------
__global__ __launch_bounds__(256)
void transpose_x_i8(const float* __restrict__ in, int8_t* __restrict__ out) {
  const int idx = blockIdx.x * 256 + threadIdx.x;       // (b, i), i fastest
  const float4* src = reinterpret_cast<const float4*>(in) + (size_t)idx * 4;
  float4 v[4];
  v[0] = src[0]; v[1] = src[1]; v[2] = src[2]; v[3] = src[3];
  const float* f = reinterpret_cast<const float*>(v);
  const int b = idx >> 11, i = idx & 2047;
  int8_t* dst = out + (size_t)b * TT * KD + i;
#pragma unroll
  for (int t = 0; t < TT; ++t) dst[(size_t)t * KD] = (int8_t)f[t];
}

static __device__ __forceinline__ v16i zero16() {
  v16i z;
#pragma unroll
  for (int i = 0; i < 16; ++i) z[i] = 0;
  return z;
}

// ---------- fused i8 GEMM (5 limbs), 2x1 register blocking + CLIF scan ----
template<int N, bool FINAL>
__global__ __launch_bounds__(512, 2)
void gemm_scan_i8(const int8_t* __restrict__ A,    // [4096][2048] spikes
                  const int8_t* __restrict__ WL,   // [5][N][2048] limbs
                  const float* __restrict__ bias,  // [N]
                  void* __restrict__ outp) {
  __shared__ union SM {
    struct {
      int8_t a[2][8 * 1024];     // [buf][(msub)*1024 + lane*16]        16 KB
      int8_t b[2][10 * 1024];    // [buf][(l*2+nsub)*1024 + lane*16]    20 KB
    } s;
    double c[8][32 * 33];        // per-wave epilogue C tile          67.6 KB
  } sm;

  const int tid = threadIdx.x;
  const int lane = tid & 63;
  const int w = tid >> 6;
  const int wy = w >> 1;          // 0..3 -> msubs {2wy, 2wy+1}
  const int nsub = w & 1;
  const int m0 = blockIdx.x * 256;
  const int n0 = blockIdx.y * 64;
  const size_t lst = (size_t)N * KD;                 // limb plane stride

  // A staging: 256 rows x 2 k-halves = 512 jobs, 1/thread
  const int arow = tid >> 1, akh = tid & 1;
  const int8_t* Asrc = A + (size_t)(m0 + arow) * KD + akh * 16;
  const int aoff = (arow >> 5) * 1024 + akh * 512 + (arow & 31) * 16;

  // B main: limbs 0..3, 64 rows x 2 kh = 512 jobs, 1/thread
  const int bl0 = tid >> 7;                          // limb 0..3
  const int brow = (tid & 127) >> 1, bkh = tid & 1;
  const int8_t* Bsrc = WL + (size_t)bl0 * lst + (size_t)(n0 + brow) * KD + bkh * 16;
  const int boff = (bl0 * 2 + (brow >> 5)) * 1024 + bkh * 512 + (brow & 31) * 16;
  // B extra: limb 4, threads 0..127 (waves 0,1 -> uniform branch per wave)
  const int xrow = tid >> 1, xkh = tid & 1;
  const int8_t* Xsrc = WL + (size_t)4 * lst + (size_t)(n0 + xrow) * KD + xkh * 16;
  const int xoff = (8 + (xrow >> 5)) * 1024 + xkh * 512 + (xrow & 31) * 16;

  v16i acc[5][2];
#pragma unroll
  for (int l = 0; l < 5; ++l) { acc[l][0] = zero16(); acc[l][1] = zero16(); }

  // prologue: tile 0 -> buf0; tile 1 -> regs
  v4i sa = *(const v4i*)Asrc;
  v4i sb = *(const v4i*)Bsrc;
  v4i sx; if (tid < 128) sx = *(const v4i*)Xsrc;
  *(v4i*)(sm.s.a[0] + aoff) = sa;
  *(v4i*)(sm.s.b[0] + boff) = sb;
  if (tid < 128) *(v4i*)(sm.s.b[0] + xoff) = sx;
  sa = *(const v4i*)(Asrc + 32);
  sb = *(const v4i*)(Bsrc + 32);
  if (tid < 128) sx = *(const v4i*)(Xsrc + 32);
  __syncthreads();

  constexpr int NT = KD / 32;
  for (int t = 0; t < NT; ++t) {
    const int cur = t & 1;
    const int8_t* ab = sm.s.a[cur];
    const int8_t* bb = sm.s.b[cur];
    const v4i a0 = *(const v4i*)(ab + (wy * 2 + 0) * 1024 + lane * 16);
    const v4i a1 = *(const v4i*)(ab + (wy * 2 + 1) * 1024 + lane * 16);
#pragma unroll
    for (int l = 0; l < 5; ++l) {
      const v4i bf = *(const v4i*)(bb + (l * 2 + nsub) * 1024 + lane * 16);
      acc[l][0] = __builtin_amdgcn_mfma_i32_32x32x32_i8(a0, bf, acc[l][0], 0, 0, 0);
      acc[l][1] = __builtin_amdgcn_mfma_i32_32x32x32_i8(a1, bf, acc[l][1], 0, 0, 0);
    }
    if (t < NT - 1) {               // stage tile t+1 into other buffer
      *(v4i*)(sm.s.a[cur ^ 1] + aoff) = sa;
      *(v4i*)(sm.s.b[cur ^ 1] + boff) = sb;
      if (tid < 128) *(v4i*)(sm.s.b[cur ^ 1] + xoff) = sx;
    }
    if (t < NT - 2) {               // prefetch tile t+2 (full iter of cover)
      sa = *(const v4i*)(Asrc + (t + 2) * 32);
      sb = *(const v4i*)(Bsrc + (t + 2) * 32);
      if (tid < 128) sx = *(const v4i*)(Xsrc + (t + 2) * 32);
    }
    __syncthreads();
  }

  // ---- decode D layout at runtime (uniform-byte MFMAs, permutation-immune)
  const int rep = (lane & 31) * 0x01010101;
  v4i rowv; rowv[0] = rep; rowv[1] = rep; rowv[2] = rep; rowv[3] = rep;
  v4i onev; onev[0] = 0x01010101; onev[1] = 0x01010101;
            onev[2] = 0x01010101; onev[3] = 0x01010101;
  const v16i drow = __builtin_amdgcn_mfma_i32_32x32x32_i8(rowv, onev, zero16(), 0, 0, 0);
  const v16i dcol = __builtin_amdgcn_mfma_i32_32x32x32_i8(onev, rowv, zero16(), 0, 0, 0);

  // ---- epilogue: 2 passes (mi); combine limbs, scatter f64, CLIF scan ----
  const int col = lane & 31;
  const int bl = lane >> 5;
  double* cw = sm.c[w];
#pragma unroll
  for (int mi = 0; mi < 2; ++mi) {
    __syncthreads();               // staging dead / previous pass done
#pragma unroll
    for (int i = 0; i < 16; ++i) {
      long long ts = acc[4][mi][i];
      ts = (ts << 8) + acc[3][mi][i];
      ts = (ts << 8) + acc[2][mi][i];
      ts = (ts << 8) + acc[1][mi][i];
      ts = (ts << 8) + acc[0][mi][i];
      cw[(drow[i] >> 5) * 33 + (dcol[i] >> 5)] = (double)ts * 0x1p-42;
    }
    __syncthreads();

    const int gn = n0 + nsub * 32 + col;              // global column
    const int gm = m0 + (wy * 2 + mi) * 32 + bl * 16; // global row of t=0
    const double bj = (double)bias[gn];
    double cc = 0.0, vv = 0.0, ss = 0.0;
    if (!FINAL) {
      int8_t* so = (int8_t*)outp;
#pragma unroll
      for (int t = 0; t < TT; ++t) {
        const double x = cw[(bl * 16 + t) * 33 + col] + bj;
        cc = cc * 0.5 + x;                    // NEURON_CDECAY
        vv = vv * 0.75 * (1.0 - ss) + cc;     // NEURON_VDECAY, soft reset
        ss = (vv > 0.5) ? 1.0 : 0.0;          // NEURON_VTH
        so[(size_t)(gm + t) * N + gn] = (int8_t)ss;
      }
    } else {
      float tot = 0.0f;
#pragma unroll
      for (int t = 0; t < TT; ++t) {
        const double x = cw[(bl * 16 + t) * 33 + col] + bj;
        cc = cc * 0.5 + x;
        vv = vv * 0.75 * (1.0 - ss) + cc;
        ss = (vv > 0.5) ? 1.0 : 0.0;
        tot += (float)ss;
      }
      ((float*)outp)[(size_t)(gm / TT) * N + gn] = tot * 0.0625f;
    }
  }
}

extern "C" void kernel_launch(void* const* d_in, const int* in_sizes, int n_in,
                              void* d_out, int out_size, void* d_ws, size_t ws_size,
                              hipStream_t stream) {
  const float* X  = (const float*)d_in[0];  // [256][2048][16]
  const float* W0 = (const float*)d_in[1];  // [2048][2048]
  const float* b0 = (const float*)d_in[2];
  const float* W1 = (const float*)d_in[3];  // [2048][2048]
  const float* b1 = (const float*)d_in[4];
  const float* Wo = (const float*)d_in[5];  // [1024][2048]
  const float* bo = (const float*)d_in[6];
  float* out = (float*)d_out;               // [256][1024]

  int8_t* base = (int8_t*)d_ws;
  int8_t* Xi8 = base;                                   // 8.39 MB
  int8_t* S0  = base + (size_t)8388608;                 // 8.39 MB
  int8_t* S1  = Xi8;                                    // reuse after layer 0
  int8_t* L0  = base + (size_t)16777216;                // 21 MB
  int8_t* L1  = base + (size_t)37748736;                // 21 MB
  int8_t* Lo  = base + (size_t)58720256;                // 10.5 MB

  prep_limbs<<<(2048 * 2048 / 4 + 255) / 256, 256, 0, stream>>>(W0, L0, 2048 * 2048);
  prep_limbs<<<(2048 * 2048 / 4 + 255) / 256, 256, 0, stream>>>(W1, L1, 2048 * 2048);
  prep_limbs<<<(1024 * 2048 / 4 + 255) / 256, 256, 0, stream>>>(Wo, Lo, 1024 * 2048);
  transpose_x_i8<<<2048, 256, 0, stream>>>(X, Xi8);

  gemm_scan_i8<2048, false><<<dim3(16, 32), 512, 0, stream>>>(Xi8, L0, b0, S0);
  gemm_scan_i8<2048, false><<<dim3(16, 32), 512, 0, stream>>>(S0, L1, b1, S1);
  gemm_scan_i8<1024, true ><<<dim3(16, 16), 512, 0, stream>>>(S1, Lo, bo, out);
}